// Round 20
// baseline (125.030 us; speedup 1.0000x reference)
//
#include <hip/hip_runtime.h>
#include <math.h>

// ---------------------------------------------------------------------------
// Round 20: modern-default f32 chain (foldlike splits tf(k,0,i), XOR-fold
// scalar bits, conditional boost-first) with THE TRANSFORM FIX:
//   log_boost = log1p(-uniform(subkey)) / alpha      [= -exponential/alpha]
// not log(uniform(subkey))/alpha as in all prior rounds. JAX _gamma_one
// log-space: "log U ~ -Exponential ... generate the exponential variate
// directly" -> jax.random.exponential(subkey) = -log1p(-uniform(subkey)).
// Single-line flip vs R5; alpha>=1 coords stay bit-exact.
// ---------------------------------------------------------------------------

struct K2 { unsigned a, b; };

__device__ __forceinline__ unsigned rotl32(unsigned v, int r) {
  return (v << r) | (v >> (32 - r));
}

__device__ __forceinline__ K2 tf2x32(K2 k, unsigned x0, unsigned x1) {
  unsigned ks0 = k.a, ks1 = k.b, ks2 = k.a ^ k.b ^ 0x1BD11BDAu;
  x0 += ks0; x1 += ks1;
#define TF_ROUND(r) { x0 += x1; x1 = rotl32(x1, (r)); x1 ^= x0; }
  TF_ROUND(13) TF_ROUND(15) TF_ROUND(26) TF_ROUND(6)
  x0 += ks1; x1 += ks2 + 1u;
  TF_ROUND(17) TF_ROUND(29) TF_ROUND(16) TF_ROUND(24)
  x0 += ks2; x1 += ks0 + 2u;
  TF_ROUND(13) TF_ROUND(15) TF_ROUND(26) TF_ROUND(6)
  x0 += ks0; x1 += ks1 + 3u;
  TF_ROUND(17) TF_ROUND(29) TF_ROUND(16) TF_ROUND(24)
  x0 += ks1; x1 += ks2 + 4u;
  TF_ROUND(13) TF_ROUND(15) TF_ROUND(26) TF_ROUND(6)
  x0 += ks2; x1 += ks0 + 5u;
#undef TF_ROUND
  return {x0, x1};
}

// foldlike split2, carry-first: carry = tf(k,0,0), sub = tf(k,0,1)
__device__ __forceinline__ void split2f(K2& key, K2& sub) {
  K2 c = tf2x32(key, 0u, 0u);
  sub = tf2x32(key, 0u, 1u);
  key = c;
}

// foldlike split3: (carry, x_key, U_key) = (out0, out1, out2)
__device__ __forceinline__ void split3f(K2& key, K2& xk, K2& Uk) {
  K2 c = tf2x32(key, 0u, 0u);
  xk = tf2x32(key, 0u, 1u);
  Uk = tf2x32(key, 0u, 2u);
  key = c;
}

// split(key, 512)[i] = tf(key, 0, i)  (foldlike)
__device__ __forceinline__ K2 split512_at(K2 k, int i) {
  return tf2x32(k, 0u, (unsigned)i);
}

// scalar (shape=()) 32-bit random_bits, partitionable: XOR-fold of tf(k,0,0)
__device__ __forceinline__ unsigned rbits32(K2 k) {
  K2 r = tf2x32(k, 0u, 0u);
  return r.a ^ r.b;
}

// uniform [0,1) from 32 random bits (JAX mantissa trick)
__device__ __forceinline__ float bits_to_u01(unsigned bits) {
  unsigned fb = (bits >> 9) | 0x3F800000u;
  return __uint_as_float(fb) - 1.0f;
}

// XLA ErfInv32 (Giles polynomial)
__device__ __forceinline__ float erfinv_xla(float x) {
#pragma clang fp contract(off)
  float w = -log1pf(-(x * x));
  float p;
  if (w < 5.0f) {
    w = w - 2.5f;
    p = 2.81022636e-08f;
    p = 3.43273939e-07f + p * w;
    p = -3.5233877e-06f + p * w;
    p = -4.39150654e-06f + p * w;
    p = 0.00021858087f + p * w;
    p = -0.00125372503f + p * w;
    p = -0.00417768164f + p * w;
    p = 0.246640727f + p * w;
    p = 1.50140941f + p * w;
  } else {
    w = sqrtf(w) - 3.0f;
    p = -0.000200214257f;
    p = 0.000100950558f + p * w;
    p = 0.00134934322f + p * w;
    p = -0.00367342844f + p * w;
    p = 0.00573950773f + p * w;
    p = -0.0076224613f + p * w;
    p = 0.00943887047f + p * w;
    p = 1.00167406f + p * w;
    p = 2.83297682f + p * w;
  }
  return p * x;
}

// jax.random.normal scalar: u = uniform(lo=-0.99999994, hi=1), sqrt(2)*erfinv(u)
__device__ __forceinline__ float normal_from_key(K2 k) {
#pragma clang fp contract(off)
  const float lo = -0.99999994f;           // nextafterf(-1, 0)
  float f = bits_to_u01(rbits32(k));
  float u = f * 2.0f + lo;                 // f32(1 - lo) == 2.0f
  u = fmaxf(lo, u);
  return 1.41421356f * erfinv_xla(u);
}

// jax.random.loggamma (_gamma_one, log_space=True), f32, conditional boost,
// boost term via EXPONENTIAL: log_boost = log1p(-u)/alpha.
__device__ float gamma_one_log(K2 key, float alpha) {
#pragma clang fp contract(off)
  float alpha_orig = alpha;
  bool boost = (alpha >= 1.0f);
  float al = boost ? alpha : (alpha + 1.0f);
  float d = al - 0.33333334f;
  float c = 0.33333334f / sqrtf(9.0f * d);
  K2 sub;
  split2f(key, sub);                       // key, subkey = split(key)
  float u_boost = bits_to_u01(rbits32(sub));
  float X = 0.0f, V = 1.0f, U = 2.0f;
  // initial state chosen so the condition holds -> always enter once
  while ((U >= 1.0f - 0.0331f * (X * X)) &&
         (logf(U) >= 0.5f * X + d * ((1.0f - V) + logf(V)))) {
    K2 xk, Uk;
    split3f(key, xk, Uk);
    float x = 0.0f, v = -1.0f;
    while (v <= 0.0f) {
      K2 s2;
      split2f(xk, s2);
      x = normal_from_key(s2);
      v = 1.0f + x * c;
    }
    X = x * x;
    V = (v * v) * v;
    U = bits_to_u01(rbits32(Uk));
  }
  float log_sample = logf(d) + logf(V);
  if (boost) return log_sample;
  // log U ~ -Exponential: exponential(subkey) = -log1p(-uniform(subkey))
  return log_sample + log1pf(-u_boost) / alpha_orig;
}

// ---------------------------------------------------------------------------
// fp64 special functions
// ---------------------------------------------------------------------------
__device__ __forceinline__ double digamma_d(double x) {
  double r = 0.0;
  while (x < 6.0) { r -= 1.0 / x; x += 1.0; }
  double f = 1.0 / (x * x);
  double ser = f * (1.0 / 12.0 -
               f * (1.0 / 120.0 -
               f * (1.0 / 252.0 -
               f * (1.0 / 240.0 -
               f * (1.0 / 132.0)))));
  return r + log(x) - 0.5 / x - ser;
}

__device__ __forceinline__ double lgamma_stir(double x) {
  double shift = 0.0;
  while (x < 8.0) { shift -= log(x); x += 1.0; }
  double f = 1.0 / (x * x);
  double ser = (1.0 / 12.0 -
               f * (1.0 / 360.0 -
               f * (1.0 / 1260.0 -
               f * (1.0 / 1680.0)))) / x;
  return shift + 0.918938533204672741780329736406 + (x - 0.5) * log(x) - x + ser;
}

// ---------------------------------------------------------------------------
// Block reductions (512 threads)
// ---------------------------------------------------------------------------
__device__ double breduce_sum(double* sd, double v) {
  int t = threadIdx.x;
  sd[t] = v; __syncthreads();
  for (int s = 256; s > 0; s >>= 1) {
    if (t < s) sd[t] += sd[t + s];
    __syncthreads();
  }
  double r = sd[0]; __syncthreads();
  return r;
}

__device__ float breduce_maxf(float* sf, float v) {
  int t = threadIdx.x;
  sf[t] = v; __syncthreads();
  for (int s = 256; s > 0; s >>= 1) {
    if (t < s) sf[t] = fmaxf(sf[t], sf[t + s]);
    __syncthreads();
  }
  float r = sf[0]; __syncthreads();
  return r;
}

__device__ float breduce_sumf(float* sf, float v) {
  int t = threadIdx.x;
  sf[t] = v; __syncthreads();
  for (int s = 256; s > 0; s >>= 1) {
    if (t < s) sf[t] += sf[t + s];
    __syncthreads();
  }
  float r = sf[0]; __syncthreads();
  return r;
}

// ---------------------------------------------------------------------------
// ws layout: [0..63] doubles: S, lgamma(S), kl. floats at +64B:
//   postf[512], mvf[512], lt[256], l1t[256], lw[256]
// ---------------------------------------------------------------------------
__global__ void __launch_bounds__(512) smv_prep_kernel(
    const float* __restrict__ post_log, const float* __restrict__ prior,
    unsigned char* __restrict__ ws) {
  double* wsd = (double*)ws;
  float* fbase = (float*)(ws + 64);
  float* postf = fbase;
  float* mvf = fbase + 512;
  float* lt = fbase + 1024;
  float* l1t = fbase + 1280;
  float* lw = fbase + 1536;
  int tid = threadIdx.x;

  if (blockIdx.x == 0) {
    // Gauss-Legendre n=256 on [-1,1] -> mapped to (0, 0.5)
    if (tid < 256) {
      const int n = 256;
      double x = cos(M_PI * (tid + 0.75) / (n + 0.5));
      double p0 = 1.0, p1 = x, dp = 1.0;
      for (int it = 0; it < 5; ++it) {
        p0 = 1.0; p1 = x;
        for (int k = 2; k <= n; ++k) {
          double pk = ((2.0 * k - 1.0) * x * p1 - (k - 1.0) * p0) / (double)k;
          p0 = p1; p1 = pk;
        }
        dp = n * (x * p1 - p0) / (x * x - 1.0);
        if (it < 4) x -= p1 / dp;
      }
      double w = 2.0 / ((1.0 - x * x) * dp * dp);
      double t = 0.25 * (x + 1.0);
      lt[tid] = (float)log(t);
      l1t[tid] = (float)log1p(-t);
      lw[tid] = (float)log(0.25 * w);
    }
    return;
  }

  // block 1: post, S, KL, and the Dirichlet draw (loggamma + softmax)
  __shared__ double sd[512];
  __shared__ float sf[512];
  float alpha = expf(post_log[tid]);
  postf[tid] = alpha;
  double p = (double)alpha;
  double S = breduce_sum(sd, p);

  K2 root = {0u, 1u};                       // jax.random.key(1)
  K2 kv = split512_at(root, tid);
  float lg = gamma_one_log(kv, alpha);
  float mx = breduce_maxf(sf, lg);          // softmax: exp(x-max)/sum
  float un = expf(lg - mx);
  float se = breduce_sumf(sf, un);
  mvf[tid] = un / se;

  double pr = (double)prior[tid];
  double dgS = digamma_d(S);
  double t3 = (p - pr) * (digamma_d(p) - dgS);
  double sum_lgp = breduce_sum(sd, lgamma(p));
  double Spr = breduce_sum(sd, pr);
  double sum_lgpr = breduce_sum(sd, lgamma(pr));
  double sum_t3 = breduce_sum(sd, t3);
  if (tid == 0) {
    double kl = lgamma(S) - sum_lgp - (lgamma(Spr) - sum_lgpr) + sum_t3;
    wsd[0] = S;
    wsd[1] = lgamma(S);
    wsd[2] = kl;
  }
}

// ---------------------------------------------------------------------------
// Main: one wave per row (8 rows / 512-thread block). Reads out[B,512] once.
// ---------------------------------------------------------------------------
__global__ void __launch_bounds__(512) smv_main_kernel(
    const int* __restrict__ vout, const int* __restrict__ y,
    const unsigned char* __restrict__ ws, float* __restrict__ dout, int B) {
  __shared__ float s_post[512], s_mv[512], s_lt[256], s_l1t[256], s_lw[256];
  const double* wsd = (const double*)ws;
  const float* fbase = (const float*)(ws + 64);
  int tid = threadIdx.x;
  s_post[tid] = fbase[tid];
  s_mv[tid] = fbase[512 + tid];
  if (tid < 256) {
    s_lt[tid] = fbase[1024 + tid];
    s_l1t[tid] = fbase[1280 + tid];
    s_lw[tid] = fbase[1536 + tid];
  }
  double S = wsd[0], lgS = wsd[1];
  float klf = (float)wsd[2];
  float Sf = (float)S;
  __syncthreads();

  int wave = tid >> 6, lane = tid & 63;
  int r = blockIdx.x * 8 + wave;
  if (r >= B) return;
  const int* row = vout + (size_t)r * 512;

  float cneg = 0.0f, mneg = 0.0f;
#pragma unroll
  for (int j = 0; j < 8; ++j) {
    int v = j * 64 + lane;
    int o = row[v];
    if (o == -1) {
      cneg += s_post[v];
      mneg += s_mv[v];
    }
  }
#pragma unroll
  for (int m = 1; m < 64; m <<= 1) {
    cneg += __shfl_xor(cneg, m);
    mneg += __shfl_xor(mneg, m);
  }

  int yr = y[r];
  float a = (yr == -1) ? cneg : (Sf - cneg);
  float b = Sf - a;
  float am1 = a - 1.0f, bm1 = b - 1.0f;

  float le[4];
#pragma unroll
  for (int k = 0; k < 4; ++k) {
    int q = lane + 64 * k;
    le[k] = s_lw[q] + am1 * s_lt[q] + bm1 * s_l1t[q];
  }
  float lm = fmaxf(fmaxf(le[0], le[1]), fmaxf(le[2], le[3]));
#pragma unroll
  for (int m = 1; m < 64; m <<= 1) lm = fmaxf(lm, __shfl_xor(lm, m));
  float ssum = expf(le[0] - lm) + expf(le[1] - lm) +
               expf(le[2] - lm) + expf(le[3] - lm);
#pragma unroll
  for (int m = 1; m < 64; m <<= 1) ssum += __shfl_xor(ssum, m);
  float lse = lm + logf(ssum);

  if (lane == 0) {
    double logB = lgamma_stir((double)a) + lgamma_stir((double)b) - lgS;
    double I = exp((double)lse - logB);
    float margin = (float)(1.0 - 2.0 * I);
    float4 o4 = make_float4(margin, mneg, 1.0f - mneg, klf);
    *(float4*)(dout + (size_t)r * 4) = o4;
  }
}

extern "C" void kernel_launch(void* const* d_in, const int* in_sizes, int n_in,
                              void* d_out, int out_size, void* d_ws,
                              size_t ws_size, hipStream_t stream) {
  const float* post_log = (const float*)d_in[0];
  const float* prior = (const float*)d_in[1];
  const int* vout = (const int*)d_in[2];
  const int* y = (const int*)d_in[3];
  float* dout = (float*)d_out;
  int B = in_sizes[3];
  unsigned char* ws = (unsigned char*)d_ws;

  hipLaunchKernelGGL(smv_prep_kernel, dim3(2), dim3(512), 0, stream,
                     post_log, prior, ws);
  int blocks = (B + 7) / 8;
  hipLaunchKernelGGL(smv_main_kernel, dim3(blocks), dim3(512), 0, stream,
                     vout, y, ws, dout, B);
}

// Round 21
// 97.726 us; speedup vs baseline: 1.2794x; 1.2794x over previous
//
#include <hip/hip_runtime.h>
#include <math.h>

// ---------------------------------------------------------------------------
// Round 21 (first perf round after R20 PASS, absmax 0.0508):
// prep kernel UNCHANGED (exact JAX chain: foldlike splits tf(k,0,i), XOR-fold
// bits, conditional boost with log1p(-u)/alpha exponential transform).
// Main kernel optimized:
//  - int4/float4 vectorized row + LDS reads (8 scalar -> 2 dwordx4 loads)
//  - 2 rows per wave (16/block), loads issued up-front, shared table reads
//  - fused 4-value butterfly reductions
//  - fp64 margin tail parallelized across lanes 0,1 (one row each)
// Predicted: main dispatch 91.5 -> ~55 us.
// ---------------------------------------------------------------------------

struct K2 { unsigned a, b; };

__device__ __forceinline__ unsigned rotl32(unsigned v, int r) {
  return (v << r) | (v >> (32 - r));
}

__device__ __forceinline__ K2 tf2x32(K2 k, unsigned x0, unsigned x1) {
  unsigned ks0 = k.a, ks1 = k.b, ks2 = k.a ^ k.b ^ 0x1BD11BDAu;
  x0 += ks0; x1 += ks1;
#define TF_ROUND(r) { x0 += x1; x1 = rotl32(x1, (r)); x1 ^= x0; }
  TF_ROUND(13) TF_ROUND(15) TF_ROUND(26) TF_ROUND(6)
  x0 += ks1; x1 += ks2 + 1u;
  TF_ROUND(17) TF_ROUND(29) TF_ROUND(16) TF_ROUND(24)
  x0 += ks2; x1 += ks0 + 2u;
  TF_ROUND(13) TF_ROUND(15) TF_ROUND(26) TF_ROUND(6)
  x0 += ks0; x1 += ks1 + 3u;
  TF_ROUND(17) TF_ROUND(29) TF_ROUND(16) TF_ROUND(24)
  x0 += ks1; x1 += ks2 + 4u;
  TF_ROUND(13) TF_ROUND(15) TF_ROUND(26) TF_ROUND(6)
  x0 += ks2; x1 += ks0 + 5u;
#undef TF_ROUND
  return {x0, x1};
}

// foldlike split2, carry-first: carry = tf(k,0,0), sub = tf(k,0,1)
__device__ __forceinline__ void split2f(K2& key, K2& sub) {
  K2 c = tf2x32(key, 0u, 0u);
  sub = tf2x32(key, 0u, 1u);
  key = c;
}

// foldlike split3: (carry, x_key, U_key) = (out0, out1, out2)
__device__ __forceinline__ void split3f(K2& key, K2& xk, K2& Uk) {
  K2 c = tf2x32(key, 0u, 0u);
  xk = tf2x32(key, 0u, 1u);
  Uk = tf2x32(key, 0u, 2u);
  key = c;
}

// split(key, 512)[i] = tf(key, 0, i)  (foldlike)
__device__ __forceinline__ K2 split512_at(K2 k, int i) {
  return tf2x32(k, 0u, (unsigned)i);
}

// scalar (shape=()) 32-bit random_bits, partitionable: XOR-fold of tf(k,0,0)
__device__ __forceinline__ unsigned rbits32(K2 k) {
  K2 r = tf2x32(k, 0u, 0u);
  return r.a ^ r.b;
}

// uniform [0,1) from 32 random bits (JAX mantissa trick)
__device__ __forceinline__ float bits_to_u01(unsigned bits) {
  unsigned fb = (bits >> 9) | 0x3F800000u;
  return __uint_as_float(fb) - 1.0f;
}

// XLA ErfInv32 (Giles polynomial)
__device__ __forceinline__ float erfinv_xla(float x) {
#pragma clang fp contract(off)
  float w = -log1pf(-(x * x));
  float p;
  if (w < 5.0f) {
    w = w - 2.5f;
    p = 2.81022636e-08f;
    p = 3.43273939e-07f + p * w;
    p = -3.5233877e-06f + p * w;
    p = -4.39150654e-06f + p * w;
    p = 0.00021858087f + p * w;
    p = -0.00125372503f + p * w;
    p = -0.00417768164f + p * w;
    p = 0.246640727f + p * w;
    p = 1.50140941f + p * w;
  } else {
    w = sqrtf(w) - 3.0f;
    p = -0.000200214257f;
    p = 0.000100950558f + p * w;
    p = 0.00134934322f + p * w;
    p = -0.00367342844f + p * w;
    p = 0.00573950773f + p * w;
    p = -0.0076224613f + p * w;
    p = 0.00943887047f + p * w;
    p = 1.00167406f + p * w;
    p = 2.83297682f + p * w;
  }
  return p * x;
}

// jax.random.normal scalar: u = uniform(lo=-0.99999994, hi=1), sqrt(2)*erfinv(u)
__device__ __forceinline__ float normal_from_key(K2 k) {
#pragma clang fp contract(off)
  const float lo = -0.99999994f;           // nextafterf(-1, 0)
  float f = bits_to_u01(rbits32(k));
  float u = f * 2.0f + lo;                 // f32(1 - lo) == 2.0f
  u = fmaxf(lo, u);
  return 1.41421356f * erfinv_xla(u);
}

// jax.random.loggamma (_gamma_one, log_space=True), f32, conditional boost,
// boost term via EXPONENTIAL: log_boost = log1p(-u)/alpha.
__device__ float gamma_one_log(K2 key, float alpha) {
#pragma clang fp contract(off)
  float alpha_orig = alpha;
  bool boost = (alpha >= 1.0f);
  float al = boost ? alpha : (alpha + 1.0f);
  float d = al - 0.33333334f;
  float c = 0.33333334f / sqrtf(9.0f * d);
  K2 sub;
  split2f(key, sub);                       // key, subkey = split(key)
  float u_boost = bits_to_u01(rbits32(sub));
  float X = 0.0f, V = 1.0f, U = 2.0f;
  while ((U >= 1.0f - 0.0331f * (X * X)) &&
         (logf(U) >= 0.5f * X + d * ((1.0f - V) + logf(V)))) {
    K2 xk, Uk;
    split3f(key, xk, Uk);
    float x = 0.0f, v = -1.0f;
    while (v <= 0.0f) {
      K2 s2;
      split2f(xk, s2);
      x = normal_from_key(s2);
      v = 1.0f + x * c;
    }
    X = x * x;
    V = (v * v) * v;
    U = bits_to_u01(rbits32(Uk));
  }
  float log_sample = logf(d) + logf(V);
  if (boost) return log_sample;
  return log_sample + log1pf(-u_boost) / alpha_orig;
}

// ---------------------------------------------------------------------------
// fp64 special functions
// ---------------------------------------------------------------------------
__device__ __forceinline__ double digamma_d(double x) {
  double r = 0.0;
  while (x < 6.0) { r -= 1.0 / x; x += 1.0; }
  double f = 1.0 / (x * x);
  double ser = f * (1.0 / 12.0 -
               f * (1.0 / 120.0 -
               f * (1.0 / 252.0 -
               f * (1.0 / 240.0 -
               f * (1.0 / 132.0)))));
  return r + log(x) - 0.5 / x - ser;
}

__device__ __forceinline__ double lgamma_stir(double x) {
  double shift = 0.0;
  while (x < 8.0) { shift -= log(x); x += 1.0; }
  double f = 1.0 / (x * x);
  double ser = (1.0 / 12.0 -
               f * (1.0 / 360.0 -
               f * (1.0 / 1260.0 -
               f * (1.0 / 1680.0)))) / x;
  return shift + 0.918938533204672741780329736406 + (x - 0.5) * log(x) - x + ser;
}

// ---------------------------------------------------------------------------
// Block reductions (512 threads)
// ---------------------------------------------------------------------------
__device__ double breduce_sum(double* sd, double v) {
  int t = threadIdx.x;
  sd[t] = v; __syncthreads();
  for (int s = 256; s > 0; s >>= 1) {
    if (t < s) sd[t] += sd[t + s];
    __syncthreads();
  }
  double r = sd[0]; __syncthreads();
  return r;
}

__device__ float breduce_maxf(float* sf, float v) {
  int t = threadIdx.x;
  sf[t] = v; __syncthreads();
  for (int s = 256; s > 0; s >>= 1) {
    if (t < s) sf[t] = fmaxf(sf[t], sf[t + s]);
    __syncthreads();
  }
  float r = sf[0]; __syncthreads();
  return r;
}

__device__ float breduce_sumf(float* sf, float v) {
  int t = threadIdx.x;
  sf[t] = v; __syncthreads();
  for (int s = 256; s > 0; s >>= 1) {
    if (t < s) sf[t] += sf[t + s];
    __syncthreads();
  }
  float r = sf[0]; __syncthreads();
  return r;
}

// ---------------------------------------------------------------------------
// ws layout: [0..63] doubles: S, lgamma(S), kl. floats at +64B:
//   postf[512], mvf[512], lt[256], l1t[256], lw[256]
// ---------------------------------------------------------------------------
__global__ void __launch_bounds__(512) smv_prep_kernel(
    const float* __restrict__ post_log, const float* __restrict__ prior,
    unsigned char* __restrict__ ws) {
  double* wsd = (double*)ws;
  float* fbase = (float*)(ws + 64);
  float* postf = fbase;
  float* mvf = fbase + 512;
  float* lt = fbase + 1024;
  float* l1t = fbase + 1280;
  float* lw = fbase + 1536;
  int tid = threadIdx.x;

  if (blockIdx.x == 0) {
    // Gauss-Legendre n=256 on [-1,1] -> mapped to (0, 0.5)
    if (tid < 256) {
      const int n = 256;
      double x = cos(M_PI * (tid + 0.75) / (n + 0.5));
      double p0 = 1.0, p1 = x, dp = 1.0;
      for (int it = 0; it < 5; ++it) {
        p0 = 1.0; p1 = x;
        for (int k = 2; k <= n; ++k) {
          double pk = ((2.0 * k - 1.0) * x * p1 - (k - 1.0) * p0) / (double)k;
          p0 = p1; p1 = pk;
        }
        dp = n * (x * p1 - p0) / (x * x - 1.0);
        if (it < 4) x -= p1 / dp;
      }
      double w = 2.0 / ((1.0 - x * x) * dp * dp);
      double t = 0.25 * (x + 1.0);
      lt[tid] = (float)log(t);
      l1t[tid] = (float)log1p(-t);
      lw[tid] = (float)log(0.25 * w);
    }
    return;
  }

  // block 1: post, S, KL, and the Dirichlet draw (loggamma + softmax)
  __shared__ double sd[512];
  __shared__ float sf[512];
  float alpha = expf(post_log[tid]);
  postf[tid] = alpha;
  double p = (double)alpha;
  double S = breduce_sum(sd, p);

  K2 root = {0u, 1u};                       // jax.random.key(1)
  K2 kv = split512_at(root, tid);
  float lg = gamma_one_log(kv, alpha);
  float mx = breduce_maxf(sf, lg);          // softmax: exp(x-max)/sum
  float un = expf(lg - mx);
  float se = breduce_sumf(sf, un);
  mvf[tid] = un / se;

  double pr = (double)prior[tid];
  double dgS = digamma_d(S);
  double t3 = (p - pr) * (digamma_d(p) - dgS);
  double sum_lgp = breduce_sum(sd, lgamma(p));
  double Spr = breduce_sum(sd, pr);
  double sum_lgpr = breduce_sum(sd, lgamma(pr));
  double sum_t3 = breduce_sum(sd, t3);
  if (tid == 0) {
    double kl = lgamma(S) - sum_lgp - (lgamma(Spr) - sum_lgpr) + sum_t3;
    wsd[0] = S;
    wsd[1] = lgamma(S);
    wsd[2] = kl;
  }
}

// ---------------------------------------------------------------------------
// Main: 2 rows per wave, 8 waves/block -> 16 rows/block. int4/float4 loads,
// fused butterfly reductions, fp64 tail split across lanes 0/1.
// ---------------------------------------------------------------------------
__global__ void __launch_bounds__(512) smv_main_kernel(
    const int* __restrict__ vout, const int* __restrict__ y,
    const unsigned char* __restrict__ ws, float* __restrict__ dout, int B) {
  __shared__ float s_post[512], s_mv[512], s_lt[256], s_l1t[256], s_lw[256];
  const double* wsd = (const double*)ws;
  const float* fbase = (const float*)(ws + 64);
  int tid = threadIdx.x;
  s_post[tid] = fbase[tid];
  s_mv[tid] = fbase[512 + tid];
  if (tid < 256) {
    s_lt[tid] = fbase[1024 + tid];
    s_l1t[tid] = fbase[1280 + tid];
    s_lw[tid] = fbase[1536 + tid];
  }
  double S = wsd[0], lgS = wsd[1];
  float klf = (float)wsd[2];
  float Sf = (float)S;
  __syncthreads();

  int wave = tid >> 6, lane = tid & 63;
  int r0 = (blockIdx.x * 8 + wave) * 2;
  if (r0 >= B) return;
  int rB_valid = (r0 + 1 < B);

  const int4* rowA = (const int4*)(vout + (size_t)r0 * 512);
  const int4* rowB = (const int4*)(vout + (size_t)(rB_valid ? r0 + 1 : r0) * 512);

  // issue all 4 row loads up-front
  int4 a0 = rowA[lane];
  int4 a1 = rowA[64 + lane];
  int4 b0 = rowB[lane];
  int4 b1 = rowB[64 + lane];

  // accumulate with shared float4 LDS reads
  float cnA = 0.0f, mnA = 0.0f, cnB = 0.0f, mnB = 0.0f;
  {
    float4 p0 = *(const float4*)&s_post[lane * 4];
    float4 m0 = *(const float4*)&s_mv[lane * 4];
    if (a0.x < 0) { cnA += p0.x; mnA += m0.x; }
    if (a0.y < 0) { cnA += p0.y; mnA += m0.y; }
    if (a0.z < 0) { cnA += p0.z; mnA += m0.z; }
    if (a0.w < 0) { cnA += p0.w; mnA += m0.w; }
    if (b0.x < 0) { cnB += p0.x; mnB += m0.x; }
    if (b0.y < 0) { cnB += p0.y; mnB += m0.y; }
    if (b0.z < 0) { cnB += p0.z; mnB += m0.z; }
    if (b0.w < 0) { cnB += p0.w; mnB += m0.w; }
    float4 p1 = *(const float4*)&s_post[256 + lane * 4];
    float4 m1 = *(const float4*)&s_mv[256 + lane * 4];
    if (a1.x < 0) { cnA += p1.x; mnA += m1.x; }
    if (a1.y < 0) { cnA += p1.y; mnA += m1.y; }
    if (a1.z < 0) { cnA += p1.z; mnA += m1.z; }
    if (a1.w < 0) { cnA += p1.w; mnA += m1.w; }
    if (b1.x < 0) { cnB += p1.x; mnB += m1.x; }
    if (b1.y < 0) { cnB += p1.y; mnB += m1.y; }
    if (b1.z < 0) { cnB += p1.z; mnB += m1.z; }
    if (b1.w < 0) { cnB += p1.w; mnB += m1.w; }
  }

  // fused 4-value butterfly
#pragma unroll
  for (int m = 1; m < 64; m <<= 1) {
    cnA += __shfl_xor(cnA, m);
    mnA += __shfl_xor(mnA, m);
    cnB += __shfl_xor(cnB, m);
    mnB += __shfl_xor(mnB, m);
  }

  int yA = y[r0];
  int yB = y[rB_valid ? r0 + 1 : r0];
  float aA = (yA == -1) ? cnA : (Sf - cnA);
  float bA = Sf - aA;
  float aB = (yB == -1) ? cnB : (Sf - cnB);
  float bB = Sf - aB;
  float amA = aA - 1.0f, bmA = bA - 1.0f;
  float amB = aB - 1.0f, bmB = bB - 1.0f;

  // quadrature: shared table reads for both rows
  float leA[4], leB[4];
#pragma unroll
  for (int k = 0; k < 4; ++k) {
    int q = lane + 64 * k;
    float lwv = s_lw[q], ltv = s_lt[q], l1v = s_l1t[q];
    leA[k] = lwv + amA * ltv + bmA * l1v;
    leB[k] = lwv + amB * ltv + bmB * l1v;
  }
  float lmA = fmaxf(fmaxf(leA[0], leA[1]), fmaxf(leA[2], leA[3]));
  float lmB = fmaxf(fmaxf(leB[0], leB[1]), fmaxf(leB[2], leB[3]));
#pragma unroll
  for (int m = 1; m < 64; m <<= 1) {
    lmA = fmaxf(lmA, __shfl_xor(lmA, m));
    lmB = fmaxf(lmB, __shfl_xor(lmB, m));
  }
  float ssA = expf(leA[0] - lmA) + expf(leA[1] - lmA) +
              expf(leA[2] - lmA) + expf(leA[3] - lmA);
  float ssB = expf(leB[0] - lmB) + expf(leB[1] - lmB) +
              expf(leB[2] - lmB) + expf(leB[3] - lmB);
#pragma unroll
  for (int m = 1; m < 64; m <<= 1) {
    ssA += __shfl_xor(ssA, m);
    ssB += __shfl_xor(ssB, m);
  }
  float lseA = lmA + logf(ssA);
  float lseB = lmB + logf(ssB);

  // fp64 margin tail: lane 0 -> row A, lane 1 -> row B (parallel)
  if (lane < 2) {
    int r = r0 + lane;
    if (r < B) {
      float a = (lane == 0) ? aA : aB;
      float b = (lane == 0) ? bA : bB;
      float lse = (lane == 0) ? lseA : lseB;
      float mneg = (lane == 0) ? mnA : mnB;
      double logB = lgamma_stir((double)a) + lgamma_stir((double)b) - lgS;
      double I = exp((double)lse - logB);
      float margin = (float)(1.0 - 2.0 * I);
      float4 o4 = make_float4(margin, mneg, 1.0f - mneg, klf);
      *(float4*)(dout + (size_t)r * 4) = o4;
    }
  }
}

extern "C" void kernel_launch(void* const* d_in, const int* in_sizes, int n_in,
                              void* d_out, int out_size, void* d_ws,
                              size_t ws_size, hipStream_t stream) {
  const float* post_log = (const float*)d_in[0];
  const float* prior = (const float*)d_in[1];
  const int* vout = (const int*)d_in[2];
  const int* y = (const int*)d_in[3];
  float* dout = (float*)d_out;
  int B = in_sizes[3];
  unsigned char* ws = (unsigned char*)d_ws;

  hipLaunchKernelGGL(smv_prep_kernel, dim3(2), dim3(512), 0, stream,
                     post_log, prior, ws);
  int blocks = (B + 15) / 16;
  hipLaunchKernelGGL(smv_main_kernel, dim3(blocks), dim3(512), 0, stream,
                     vout, y, ws, dout, B);
}

// Round 22
// 94.951 us; speedup vs baseline: 1.3168x; 1.0292x over previous
//
#include <hip/hip_runtime.h>
#include <math.h>

// ---------------------------------------------------------------------------
// Round 22: margin-table restructure (R20 RNG chain untouched, bit-exact).
//  - prep: Newton 5->3 evals for GL nodes; stores Mtot (f32 sum of mv).
//  - NEW mtab kernel (32x512): margin(a) on 16384-pt grid over [0,S]
//    (online logsumexp over 256 GL nodes + f64 logB). Interp err ~8e-7.
//  - main: 4 rows/wave, dot-form accumulate (cvt+2fmac per elem), single
//    butterfly phase, margin via 2-load table lerp. No per-row exp/lgamma.
// Predicted: dur 97.7 -> ~55 us; absmax stays 0.0508.
// ---------------------------------------------------------------------------

struct K2 { unsigned a, b; };

__device__ __forceinline__ unsigned rotl32(unsigned v, int r) {
  return (v << r) | (v >> (32 - r));
}

__device__ __forceinline__ K2 tf2x32(K2 k, unsigned x0, unsigned x1) {
  unsigned ks0 = k.a, ks1 = k.b, ks2 = k.a ^ k.b ^ 0x1BD11BDAu;
  x0 += ks0; x1 += ks1;
#define TF_ROUND(r) { x0 += x1; x1 = rotl32(x1, (r)); x1 ^= x0; }
  TF_ROUND(13) TF_ROUND(15) TF_ROUND(26) TF_ROUND(6)
  x0 += ks1; x1 += ks2 + 1u;
  TF_ROUND(17) TF_ROUND(29) TF_ROUND(16) TF_ROUND(24)
  x0 += ks2; x1 += ks0 + 2u;
  TF_ROUND(13) TF_ROUND(15) TF_ROUND(26) TF_ROUND(6)
  x0 += ks0; x1 += ks1 + 3u;
  TF_ROUND(17) TF_ROUND(29) TF_ROUND(16) TF_ROUND(24)
  x0 += ks1; x1 += ks2 + 4u;
  TF_ROUND(13) TF_ROUND(15) TF_ROUND(26) TF_ROUND(6)
  x0 += ks2; x1 += ks0 + 5u;
#undef TF_ROUND
  return {x0, x1};
}

// foldlike split2, carry-first: carry = tf(k,0,0), sub = tf(k,0,1)
__device__ __forceinline__ void split2f(K2& key, K2& sub) {
  K2 c = tf2x32(key, 0u, 0u);
  sub = tf2x32(key, 0u, 1u);
  key = c;
}

// foldlike split3: (carry, x_key, U_key) = (out0, out1, out2)
__device__ __forceinline__ void split3f(K2& key, K2& xk, K2& Uk) {
  K2 c = tf2x32(key, 0u, 0u);
  xk = tf2x32(key, 0u, 1u);
  Uk = tf2x32(key, 0u, 2u);
  key = c;
}

// split(key, 512)[i] = tf(key, 0, i)  (foldlike)
__device__ __forceinline__ K2 split512_at(K2 k, int i) {
  return tf2x32(k, 0u, (unsigned)i);
}

// scalar 32-bit random_bits, partitionable: XOR-fold of tf(k,0,0)
__device__ __forceinline__ unsigned rbits32(K2 k) {
  K2 r = tf2x32(k, 0u, 0u);
  return r.a ^ r.b;
}

__device__ __forceinline__ float bits_to_u01(unsigned bits) {
  unsigned fb = (bits >> 9) | 0x3F800000u;
  return __uint_as_float(fb) - 1.0f;
}

// XLA ErfInv32 (Giles polynomial)
__device__ __forceinline__ float erfinv_xla(float x) {
#pragma clang fp contract(off)
  float w = -log1pf(-(x * x));
  float p;
  if (w < 5.0f) {
    w = w - 2.5f;
    p = 2.81022636e-08f;
    p = 3.43273939e-07f + p * w;
    p = -3.5233877e-06f + p * w;
    p = -4.39150654e-06f + p * w;
    p = 0.00021858087f + p * w;
    p = -0.00125372503f + p * w;
    p = -0.00417768164f + p * w;
    p = 0.246640727f + p * w;
    p = 1.50140941f + p * w;
  } else {
    w = sqrtf(w) - 3.0f;
    p = -0.000200214257f;
    p = 0.000100950558f + p * w;
    p = 0.00134934322f + p * w;
    p = -0.00367342844f + p * w;
    p = 0.00573950773f + p * w;
    p = -0.0076224613f + p * w;
    p = 0.00943887047f + p * w;
    p = 1.00167406f + p * w;
    p = 2.83297682f + p * w;
  }
  return p * x;
}

__device__ __forceinline__ float normal_from_key(K2 k) {
#pragma clang fp contract(off)
  const float lo = -0.99999994f;           // nextafterf(-1, 0)
  float f = bits_to_u01(rbits32(k));
  float u = f * 2.0f + lo;                 // f32(1 - lo) == 2.0f
  u = fmaxf(lo, u);
  return 1.41421356f * erfinv_xla(u);
}

// jax.random.loggamma (_gamma_one, log_space=True), f32, conditional boost,
// boost term via EXPONENTIAL: log_boost = log1p(-u)/alpha.   [R20, verified]
__device__ float gamma_one_log(K2 key, float alpha) {
#pragma clang fp contract(off)
  float alpha_orig = alpha;
  bool boost = (alpha >= 1.0f);
  float al = boost ? alpha : (alpha + 1.0f);
  float d = al - 0.33333334f;
  float c = 0.33333334f / sqrtf(9.0f * d);
  K2 sub;
  split2f(key, sub);
  float u_boost = bits_to_u01(rbits32(sub));
  float X = 0.0f, V = 1.0f, U = 2.0f;
  while ((U >= 1.0f - 0.0331f * (X * X)) &&
         (logf(U) >= 0.5f * X + d * ((1.0f - V) + logf(V)))) {
    K2 xk, Uk;
    split3f(key, xk, Uk);
    float x = 0.0f, v = -1.0f;
    while (v <= 0.0f) {
      K2 s2;
      split2f(xk, s2);
      x = normal_from_key(s2);
      v = 1.0f + x * c;
    }
    X = x * x;
    V = (v * v) * v;
    U = bits_to_u01(rbits32(Uk));
  }
  float log_sample = logf(d) + logf(V);
  if (boost) return log_sample;
  return log_sample + log1pf(-u_boost) / alpha_orig;
}

// ---------------------------------------------------------------------------
// fp64 special functions
// ---------------------------------------------------------------------------
__device__ __forceinline__ double digamma_d(double x) {
  double r = 0.0;
  while (x < 6.0) { r -= 1.0 / x; x += 1.0; }
  double f = 1.0 / (x * x);
  double ser = f * (1.0 / 12.0 -
               f * (1.0 / 120.0 -
               f * (1.0 / 252.0 -
               f * (1.0 / 240.0 -
               f * (1.0 / 132.0)))));
  return r + log(x) - 0.5 / x - ser;
}

__device__ __forceinline__ double lgamma_stir(double x) {
  double shift = 0.0;
  while (x < 8.0) { shift -= log(x); x += 1.0; }
  double f = 1.0 / (x * x);
  double ser = (1.0 / 12.0 -
               f * (1.0 / 360.0 -
               f * (1.0 / 1260.0 -
               f * (1.0 / 1680.0)))) / x;
  return shift + 0.918938533204672741780329736406 + (x - 0.5) * log(x) - x + ser;
}

// ---------------------------------------------------------------------------
// Block reductions (512 threads)
// ---------------------------------------------------------------------------
__device__ double breduce_sum(double* sd, double v) {
  int t = threadIdx.x;
  sd[t] = v; __syncthreads();
  for (int s = 256; s > 0; s >>= 1) {
    if (t < s) sd[t] += sd[t + s];
    __syncthreads();
  }
  double r = sd[0]; __syncthreads();
  return r;
}

__device__ float breduce_maxf(float* sf, float v) {
  int t = threadIdx.x;
  sf[t] = v; __syncthreads();
  for (int s = 256; s > 0; s >>= 1) {
    if (t < s) sf[t] = fmaxf(sf[t], sf[t + s]);
    __syncthreads();
  }
  float r = sf[0]; __syncthreads();
  return r;
}

__device__ float breduce_sumf(float* sf, float v) {
  int t = threadIdx.x;
  sf[t] = v; __syncthreads();
  for (int s = 256; s > 0; s >>= 1) {
    if (t < s) sf[t] += sf[t + s];
    __syncthreads();
  }
  float r = sf[0]; __syncthreads();
  return r;
}

// ---------------------------------------------------------------------------
// ws layout: [0..63] doubles: S, lgamma(S), kl, Mtot. floats at +64B:
//   postf[512] @0, mvf[512] @512, lt[256] @1024, l1t[256] @1280,
//   lw[256] @1536, mtab[16384] @1792
// ---------------------------------------------------------------------------
#define MTAB_N 16384

__global__ void __launch_bounds__(512) smv_prep_kernel(
    const float* __restrict__ post_log, const float* __restrict__ prior,
    unsigned char* __restrict__ ws) {
  double* wsd = (double*)ws;
  float* fbase = (float*)(ws + 64);
  float* postf = fbase;
  float* mvf = fbase + 512;
  float* lt = fbase + 1024;
  float* l1t = fbase + 1280;
  float* lw = fbase + 1536;
  int tid = threadIdx.x;

  if (blockIdx.x == 0) {
    // Gauss-Legendre n=256 on [-1,1] -> (0,0.5); 3 evals (2 Newton updates)
    if (tid < 256) {
      const int n = 256;
      double x = cos(M_PI * (tid + 0.75) / (n + 0.5));
      double p0 = 1.0, p1 = x, dp = 1.0;
      for (int it = 0; it < 3; ++it) {
        p0 = 1.0; p1 = x;
        for (int k = 2; k <= n; ++k) {
          double pk = ((2.0 * k - 1.0) * x * p1 - (k - 1.0) * p0) / (double)k;
          p0 = p1; p1 = pk;
        }
        dp = n * (x * p1 - p0) / (x * x - 1.0);
        if (it < 2) x -= p1 / dp;
      }
      double w = 2.0 / ((1.0 - x * x) * dp * dp);
      double t = 0.25 * (x + 1.0);
      lt[tid] = (float)log(t);
      l1t[tid] = (float)log1p(-t);
      lw[tid] = (float)log(0.25 * w);
    }
    return;
  }

  // block 1: post, S, KL, and the Dirichlet draw (R20 chain, bit-exact)
  __shared__ double sd[512];
  __shared__ float sf[512];
  float alpha = expf(post_log[tid]);
  postf[tid] = alpha;
  double p = (double)alpha;
  double S = breduce_sum(sd, p);

  K2 root = {0u, 1u};                       // jax.random.key(1)
  K2 kv = split512_at(root, tid);
  float lg = gamma_one_log(kv, alpha);
  float mx = breduce_maxf(sf, lg);
  float un = expf(lg - mx);
  float se = breduce_sumf(sf, un);
  float mvv = un / se;
  mvf[tid] = mvv;
  float mtot = breduce_sumf(sf, mvv);       // f32 total of mv

  double pr = (double)prior[tid];
  double dgS = digamma_d(S);
  double t3 = (p - pr) * (digamma_d(p) - dgS);
  double sum_lgp = breduce_sum(sd, lgamma(p));
  double Spr = breduce_sum(sd, pr);
  double sum_lgpr = breduce_sum(sd, lgamma(pr));
  double sum_t3 = breduce_sum(sd, t3);
  if (tid == 0) {
    double kl = lgamma(S) - sum_lgp - (lgamma(Spr) - sum_lgpr) + sum_t3;
    wsd[0] = S;
    wsd[1] = lgamma(S);
    wsd[2] = kl;
    wsd[3] = (double)mtot;
  }
}

// ---------------------------------------------------------------------------
// Margin table: mtab[i] = 1 - 2*I_{0.5}(a_i, S-a_i), a_i = S*i/(MTAB_N-1).
// 32 blocks x 512 threads; online logsumexp over the 256 GL nodes.
// ---------------------------------------------------------------------------
__global__ void __launch_bounds__(512) smv_mtab_kernel(
    unsigned char* __restrict__ ws) {
  const double* wsd = (const double*)ws;
  float* fbase = (float*)(ws + 64);
  const float* lt = fbase + 1024;
  const float* l1t = fbase + 1280;
  const float* lw = fbase + 1536;
  float* mtab = fbase + 1792;
  __shared__ float slt[256], sl1t[256], slw[256];
  int tid = threadIdx.x;
  if (tid < 256) {
    slt[tid] = lt[tid];
    sl1t[tid] = l1t[tid];
    slw[tid] = lw[tid];
  }
  __syncthreads();

  int idx = blockIdx.x * 512 + tid;
  if (idx >= MTAB_N) return;
  double S = wsd[0], lgS = wsd[1];
  double ad = S * (double)idx / (double)(MTAB_N - 1);
  // clamp away from 0/S to keep lgamma finite (queries never hit extremes)
  ad = fmin(fmax(ad, 0.05), S - 0.05);
  float a = (float)ad;
  float b = (float)(S - ad);
  float am1 = a - 1.0f, bm1 = b - 1.0f;

  float m = -1e30f, s = 0.0f;
  for (int q = 0; q < 256; ++q) {
    float le = slw[q] + am1 * slt[q] + bm1 * sl1t[q];
    if (le > m) {
      s = s * expf(m - le) + 1.0f;
      m = le;
    } else {
      s += expf(le - m);
    }
  }
  float lse = m + logf(s);
  double logB = lgamma_stir(ad) + lgamma_stir((double)(S - ad)) - lgS;
  double I = exp((double)lse - logB);
  mtab[idx] = (float)(1.0 - 2.0 * I);
}

// ---------------------------------------------------------------------------
// Main: 4 rows/wave (32/block). Dot-form accumulate, single butterfly,
// margin via table lerp. Reads out[B,512] once, coalesced int4.
// ---------------------------------------------------------------------------
__global__ void __launch_bounds__(512) smv_main_kernel(
    const int* __restrict__ vout, const int* __restrict__ y,
    const unsigned char* __restrict__ ws, float* __restrict__ dout, int B) {
  __shared__ float s_post[512], s_mv[512];
  const double* wsd = (const double*)ws;
  const float* fbase = (const float*)(ws + 64);
  const float* mtab = fbase + 1792;
  int tid = threadIdx.x;
  s_post[tid] = fbase[tid];
  s_mv[tid] = fbase[512 + tid];
  float Sf = (float)wsd[0];
  float Mtot = (float)wsd[3];
  float klf = (float)wsd[2];
  float scale = (float)(MTAB_N - 1) / Sf;
  __syncthreads();

  int wave = tid >> 6, lane = tid & 63;
  int r0 = (blockIdx.x * 8 + wave) * 4;
  if (r0 >= B) return;

  // row base pointers (clamped for tail safety)
  const int4* rp0 = (const int4*)(vout + (size_t)r0 * 512);
  const int4* rp1 = (const int4*)(vout + (size_t)min(r0 + 1, B - 1) * 512);
  const int4* rp2 = (const int4*)(vout + (size_t)min(r0 + 2, B - 1) * 512);
  const int4* rp3 = (const int4*)(vout + (size_t)min(r0 + 3, B - 1) * 512);

  // issue all 8 loads up-front
  int4 v00 = rp0[lane], v01 = rp0[64 + lane];
  int4 v10 = rp1[lane], v11 = rp1[64 + lane];
  int4 v20 = rp2[lane], v21 = rp2[64 + lane];
  int4 v30 = rp3[lane], v31 = rp3[64 + lane];

  float4 p0 = *(const float4*)&s_post[lane * 4];
  float4 m0 = *(const float4*)&s_mv[lane * 4];
  float4 p1 = *(const float4*)&s_post[256 + lane * 4];
  float4 m1 = *(const float4*)&s_mv[256 + lane * 4];

  float dP0 = 0.f, dM0 = 0.f, dP1 = 0.f, dM1 = 0.f;
  float dP2 = 0.f, dM2 = 0.f, dP3 = 0.f, dM3 = 0.f;

#define ACC(dP, dM, c, pp, mm)                        \
  {                                                   \
    float ox = (float)(c).x, oy = (float)(c).y,       \
          oz = (float)(c).z, ow = (float)(c).w;       \
    dP = fmaf(ox, (pp).x, dP); dM = fmaf(ox, (mm).x, dM); \
    dP = fmaf(oy, (pp).y, dP); dM = fmaf(oy, (mm).y, dM); \
    dP = fmaf(oz, (pp).z, dP); dM = fmaf(oz, (mm).z, dM); \
    dP = fmaf(ow, (pp).w, dP); dM = fmaf(ow, (mm).w, dM); \
  }
  ACC(dP0, dM0, v00, p0, m0) ACC(dP0, dM0, v01, p1, m1)
  ACC(dP1, dM1, v10, p0, m0) ACC(dP1, dM1, v11, p1, m1)
  ACC(dP2, dM2, v20, p0, m0) ACC(dP2, dM2, v21, p1, m1)
  ACC(dP3, dM3, v30, p0, m0) ACC(dP3, dM3, v31, p1, m1)
#undef ACC

#pragma unroll
  for (int m = 1; m < 64; m <<= 1) {
    dP0 += __shfl_xor(dP0, m); dM0 += __shfl_xor(dM0, m);
    dP1 += __shfl_xor(dP1, m); dM1 += __shfl_xor(dM1, m);
    dP2 += __shfl_xor(dP2, m); dM2 += __shfl_xor(dM2, m);
    dP3 += __shfl_xor(dP3, m); dM3 += __shfl_xor(dM3, m);
  }

  if (lane < 4) {
    int r = r0 + lane;
    if (r < B) {
      float dP = (lane == 0) ? dP0 : (lane == 1) ? dP1 : (lane == 2) ? dP2 : dP3;
      float dM = (lane == 0) ? dM0 : (lane == 1) ? dM1 : (lane == 2) ? dM2 : dM3;
      float cneg = (Sf - dP) * 0.5f;       // sum of post where out == -1
      float mneg = (Mtot - dM) * 0.5f;     // sum of mv   where out == -1
      int yr = y[r];
      float a = (yr == -1) ? cneg : (Sf - cneg);
      float x = a * scale;
      x = fminf(fmaxf(x, 0.0f), (float)(MTAB_N - 1) - 1.001f);
      int i = (int)x;
      float fr = x - (float)i;
      float t0 = mtab[i], t1 = mtab[i + 1];
      float margin = fmaf(fr, t1 - t0, t0);
      float4 o4 = make_float4(margin, mneg, 1.0f - mneg, klf);
      *(float4*)(dout + (size_t)r * 4) = o4;
    }
  }
}

extern "C" void kernel_launch(void* const* d_in, const int* in_sizes, int n_in,
                              void* d_out, int out_size, void* d_ws,
                              size_t ws_size, hipStream_t stream) {
  const float* post_log = (const float*)d_in[0];
  const float* prior = (const float*)d_in[1];
  const int* vout = (const int*)d_in[2];
  const int* y = (const int*)d_in[3];
  float* dout = (float*)d_out;
  int B = in_sizes[3];
  unsigned char* ws = (unsigned char*)d_ws;

  hipLaunchKernelGGL(smv_prep_kernel, dim3(2), dim3(512), 0, stream,
                     post_log, prior, ws);
  hipLaunchKernelGGL(smv_mtab_kernel, dim3(MTAB_N / 512), dim3(512), 0, stream,
                     ws);
  int blocks = (B + 31) / 32;
  hipLaunchKernelGGL(smv_main_kernel, dim3(blocks), dim3(512), 0, stream,
                     vout, y, ws, dout, B);
}

// Round 23
// 73.167 us; speedup vs baseline: 1.7088x; 1.2977x over previous
//
#include <hip/hip_runtime.h>
#include <math.h>

// ---------------------------------------------------------------------------
// Round 23: fuse prep+mtab into one 33-block setup kernel; Legendre nodes via
// Tricomi guess + ONE Newton eval + ODE-corrected derivative (3x shorter
// serial f64 chain). Block 0 = R20/R22 gamma/KL/mv chain, bit-exact.
// Blocks 1..32 self-contain: recompute S (bit-identical breduce), build GL
// table in-block, emit 512 margin-table points each. Main kernel = R22.
// Predicted: dur 95 -> ~70 us; absmax stays 0.05078125.
// ---------------------------------------------------------------------------

struct K2 { unsigned a, b; };

__device__ __forceinline__ unsigned rotl32(unsigned v, int r) {
  return (v << r) | (v >> (32 - r));
}

__device__ __forceinline__ K2 tf2x32(K2 k, unsigned x0, unsigned x1) {
  unsigned ks0 = k.a, ks1 = k.b, ks2 = k.a ^ k.b ^ 0x1BD11BDAu;
  x0 += ks0; x1 += ks1;
#define TF_ROUND(r) { x0 += x1; x1 = rotl32(x1, (r)); x1 ^= x0; }
  TF_ROUND(13) TF_ROUND(15) TF_ROUND(26) TF_ROUND(6)
  x0 += ks1; x1 += ks2 + 1u;
  TF_ROUND(17) TF_ROUND(29) TF_ROUND(16) TF_ROUND(24)
  x0 += ks2; x1 += ks0 + 2u;
  TF_ROUND(13) TF_ROUND(15) TF_ROUND(26) TF_ROUND(6)
  x0 += ks0; x1 += ks1 + 3u;
  TF_ROUND(17) TF_ROUND(29) TF_ROUND(16) TF_ROUND(24)
  x0 += ks1; x1 += ks2 + 4u;
  TF_ROUND(13) TF_ROUND(15) TF_ROUND(26) TF_ROUND(6)
  x0 += ks2; x1 += ks0 + 5u;
#undef TF_ROUND
  return {x0, x1};
}

__device__ __forceinline__ void split2f(K2& key, K2& sub) {
  K2 c = tf2x32(key, 0u, 0u);
  sub = tf2x32(key, 0u, 1u);
  key = c;
}

__device__ __forceinline__ void split3f(K2& key, K2& xk, K2& Uk) {
  K2 c = tf2x32(key, 0u, 0u);
  xk = tf2x32(key, 0u, 1u);
  Uk = tf2x32(key, 0u, 2u);
  key = c;
}

__device__ __forceinline__ K2 split512_at(K2 k, int i) {
  return tf2x32(k, 0u, (unsigned)i);
}

__device__ __forceinline__ unsigned rbits32(K2 k) {
  K2 r = tf2x32(k, 0u, 0u);
  return r.a ^ r.b;
}

__device__ __forceinline__ float bits_to_u01(unsigned bits) {
  unsigned fb = (bits >> 9) | 0x3F800000u;
  return __uint_as_float(fb) - 1.0f;
}

// XLA ErfInv32 (Giles polynomial)
__device__ __forceinline__ float erfinv_xla(float x) {
#pragma clang fp contract(off)
  float w = -log1pf(-(x * x));
  float p;
  if (w < 5.0f) {
    w = w - 2.5f;
    p = 2.81022636e-08f;
    p = 3.43273939e-07f + p * w;
    p = -3.5233877e-06f + p * w;
    p = -4.39150654e-06f + p * w;
    p = 0.00021858087f + p * w;
    p = -0.00125372503f + p * w;
    p = -0.00417768164f + p * w;
    p = 0.246640727f + p * w;
    p = 1.50140941f + p * w;
  } else {
    w = sqrtf(w) - 3.0f;
    p = -0.000200214257f;
    p = 0.000100950558f + p * w;
    p = 0.00134934322f + p * w;
    p = -0.00367342844f + p * w;
    p = 0.00573950773f + p * w;
    p = -0.0076224613f + p * w;
    p = 0.00943887047f + p * w;
    p = 1.00167406f + p * w;
    p = 2.83297682f + p * w;
  }
  return p * x;
}

__device__ __forceinline__ float normal_from_key(K2 k) {
#pragma clang fp contract(off)
  const float lo = -0.99999994f;           // nextafterf(-1, 0)
  float f = bits_to_u01(rbits32(k));
  float u = f * 2.0f + lo;                 // f32(1 - lo) == 2.0f
  u = fmaxf(lo, u);
  return 1.41421356f * erfinv_xla(u);
}

// jax.random.loggamma (_gamma_one, log_space=True), f32, conditional boost,
// boost term via EXPONENTIAL: log_boost = log1p(-u)/alpha.   [R20, verified]
__device__ float gamma_one_log(K2 key, float alpha) {
#pragma clang fp contract(off)
  float alpha_orig = alpha;
  bool boost = (alpha >= 1.0f);
  float al = boost ? alpha : (alpha + 1.0f);
  float d = al - 0.33333334f;
  float c = 0.33333334f / sqrtf(9.0f * d);
  K2 sub;
  split2f(key, sub);
  float u_boost = bits_to_u01(rbits32(sub));
  float X = 0.0f, V = 1.0f, U = 2.0f;
  while ((U >= 1.0f - 0.0331f * (X * X)) &&
         (logf(U) >= 0.5f * X + d * ((1.0f - V) + logf(V)))) {
    K2 xk, Uk;
    split3f(key, xk, Uk);
    float x = 0.0f, v = -1.0f;
    while (v <= 0.0f) {
      K2 s2;
      split2f(xk, s2);
      x = normal_from_key(s2);
      v = 1.0f + x * c;
    }
    X = x * x;
    V = (v * v) * v;
    U = bits_to_u01(rbits32(Uk));
  }
  float log_sample = logf(d) + logf(V);
  if (boost) return log_sample;
  return log_sample + log1pf(-u_boost) / alpha_orig;
}

// fp64 special functions
__device__ __forceinline__ double digamma_d(double x) {
  double r = 0.0;
  while (x < 6.0) { r -= 1.0 / x; x += 1.0; }
  double f = 1.0 / (x * x);
  double ser = f * (1.0 / 12.0 -
               f * (1.0 / 120.0 -
               f * (1.0 / 252.0 -
               f * (1.0 / 240.0 -
               f * (1.0 / 132.0)))));
  return r + log(x) - 0.5 / x - ser;
}

__device__ __forceinline__ double lgamma_stir(double x) {
  double shift = 0.0;
  while (x < 8.0) { shift -= log(x); x += 1.0; }
  double f = 1.0 / (x * x);
  double ser = (1.0 / 12.0 -
               f * (1.0 / 360.0 -
               f * (1.0 / 1260.0 -
               f * (1.0 / 1680.0)))) / x;
  return shift + 0.918938533204672741780329736406 + (x - 0.5) * log(x) - x + ser;
}

// Block reductions (512 threads)
__device__ double breduce_sum(double* sd, double v) {
  int t = threadIdx.x;
  sd[t] = v; __syncthreads();
  for (int s = 256; s > 0; s >>= 1) {
    if (t < s) sd[t] += sd[t + s];
    __syncthreads();
  }
  double r = sd[0]; __syncthreads();
  return r;
}

__device__ float breduce_maxf(float* sf, float v) {
  int t = threadIdx.x;
  sf[t] = v; __syncthreads();
  for (int s = 256; s > 0; s >>= 1) {
    if (t < s) sf[t] = fmaxf(sf[t], sf[t + s]);
    __syncthreads();
  }
  float r = sf[0]; __syncthreads();
  return r;
}

__device__ float breduce_sumf(float* sf, float v) {
  int t = threadIdx.x;
  sf[t] = v; __syncthreads();
  for (int s = 256; s > 0; s >>= 1) {
    if (t < s) sf[t] += sf[t + s];
    __syncthreads();
  }
  float r = sf[0]; __syncthreads();
  return r;
}

// ---------------------------------------------------------------------------
// ws layout: [0..63] doubles: S, lgamma(S), kl, Mtot. floats at +64B:
//   postf[512] @0, mvf[512] @512, (reserved 1024..1791), mtab[16384] @1792
// ---------------------------------------------------------------------------
#define MTAB_N 16384

__global__ void __launch_bounds__(512) smv_setup_kernel(
    const float* __restrict__ post_log, const float* __restrict__ prior,
    unsigned char* __restrict__ ws) {
  double* wsd = (double*)ws;
  float* fbase = (float*)(ws + 64);
  float* postf = fbase;
  float* mvf = fbase + 512;
  float* mtab = fbase + 1792;
  int tid = threadIdx.x;
  __shared__ double sd[512];

  if (blockIdx.x == 0) {
    // gamma draw + mv + Mtot + KL + S  (R20 chain, bit-exact, unchanged)
    __shared__ float sf[512];
    float alpha = expf(post_log[tid]);
    postf[tid] = alpha;
    double p = (double)alpha;
    double S = breduce_sum(sd, p);

    K2 root = {0u, 1u};                     // jax.random.key(1)
    K2 kv = split512_at(root, tid);
    float lg = gamma_one_log(kv, alpha);
    float mx = breduce_maxf(sf, lg);
    float un = expf(lg - mx);
    float se = breduce_sumf(sf, un);
    float mvv = un / se;
    mvf[tid] = mvv;
    float mtot = breduce_sumf(sf, mvv);

    double pr = (double)prior[tid];
    double dgS = digamma_d(S);
    double t3 = (p - pr) * (digamma_d(p) - dgS);
    double sum_lgp = breduce_sum(sd, lgamma(p));
    double Spr = breduce_sum(sd, pr);
    double sum_lgpr = breduce_sum(sd, lgamma(pr));
    double sum_t3 = breduce_sum(sd, t3);
    if (tid == 0) {
      double kl = lgamma(S) - sum_lgp - (lgamma(Spr) - sum_lgpr) + sum_t3;
      wsd[0] = S;
      wsd[1] = lgamma(S);
      wsd[2] = kl;
      wsd[3] = (double)mtot;
    }
    return;
  }

  // blocks 1..32: self-contained margin-table computation
  // (a) S via the SAME breduce algorithm -> bit-identical to block 0's S
  double S = breduce_sum(sd, (double)expf(post_log[tid]));
  double lgS = lgamma(S);

  // (b) GL-256 nodes: Tricomi guess + ONE Newton eval + ODE-corrected dp
  __shared__ float slt[256], sl1t[256], slw[256];
  if (tid < 256) {
    const int n = 256;
    const double nn = (double)n;
    double th = M_PI * (tid + 0.75) / (nn + 0.5);
    double corr = 1.0 - 1.0 / (8.0 * nn * nn) + 1.0 / (8.0 * nn * nn * nn);
    double x = corr * cos(th);
    double p0 = 1.0, p1 = x;
    for (int k = 2; k <= n; ++k) {
      double pk = ((2.0 * k - 1.0) * x * p1 - (k - 1.0) * p0) / (double)k;
      p0 = p1; p1 = pk;
    }
    double dp = nn * (x * p1 - p0) / (x * x - 1.0);
    double dx = -p1 / dp;                       // Newton step
    // p'' from Legendre ODE: (1-x^2)p'' = 2x p' - n(n+1) p
    double d2p = (2.0 * x * dp - nn * (nn + 1.0) * p1) / (1.0 - x * x);
    double xn = x + dx;
    double dpn = dp + d2p * dx;                 // derivative at the root
    double w = 2.0 / ((1.0 - xn * xn) * dpn * dpn);
    double t = 0.25 * (xn + 1.0);
    slt[tid] = (float)log(t);
    sl1t[tid] = (float)log1p(-t);
    slw[tid] = (float)log(0.25 * w);
  }
  __syncthreads();

  // (c) one margin point per thread
  int idx = (blockIdx.x - 1) * 512 + tid;
  double ad = S * (double)idx / (double)(MTAB_N - 1);
  ad = fmin(fmax(ad, 0.05), S - 0.05);
  float a = (float)ad;
  float b = (float)(S - ad);
  float am1 = a - 1.0f, bm1 = b - 1.0f;

  float m = -1e30f, s = 0.0f;
  for (int q = 0; q < 256; ++q) {
    float le = slw[q] + am1 * slt[q] + bm1 * sl1t[q];
    if (le > m) {
      s = s * expf(m - le) + 1.0f;
      m = le;
    } else {
      s += expf(le - m);
    }
  }
  float lse = m + logf(s);
  double logB = lgamma_stir(ad) + lgamma_stir((double)(S - ad)) - lgS;
  double I = exp((double)lse - logB);
  mtab[idx] = (float)(1.0 - 2.0 * I);
}

// ---------------------------------------------------------------------------
// Main: 4 rows/wave (32/block). Dot-form accumulate, single butterfly,
// margin via table lerp. Reads out[B,512] once, coalesced int4.  [R22]
// ---------------------------------------------------------------------------
__global__ void __launch_bounds__(512) smv_main_kernel(
    const int* __restrict__ vout, const int* __restrict__ y,
    const unsigned char* __restrict__ ws, float* __restrict__ dout, int B) {
  __shared__ float s_post[512], s_mv[512];
  const double* wsd = (const double*)ws;
  const float* fbase = (const float*)(ws + 64);
  const float* mtab = fbase + 1792;
  int tid = threadIdx.x;
  s_post[tid] = fbase[tid];
  s_mv[tid] = fbase[512 + tid];
  float Sf = (float)wsd[0];
  float Mtot = (float)wsd[3];
  float klf = (float)wsd[2];
  float scale = (float)(MTAB_N - 1) / Sf;
  __syncthreads();

  int wave = tid >> 6, lane = tid & 63;
  int r0 = (blockIdx.x * 8 + wave) * 4;
  if (r0 >= B) return;

  const int4* rp0 = (const int4*)(vout + (size_t)r0 * 512);
  const int4* rp1 = (const int4*)(vout + (size_t)min(r0 + 1, B - 1) * 512);
  const int4* rp2 = (const int4*)(vout + (size_t)min(r0 + 2, B - 1) * 512);
  const int4* rp3 = (const int4*)(vout + (size_t)min(r0 + 3, B - 1) * 512);

  int4 v00 = rp0[lane], v01 = rp0[64 + lane];
  int4 v10 = rp1[lane], v11 = rp1[64 + lane];
  int4 v20 = rp2[lane], v21 = rp2[64 + lane];
  int4 v30 = rp3[lane], v31 = rp3[64 + lane];

  float4 p0 = *(const float4*)&s_post[lane * 4];
  float4 m0 = *(const float4*)&s_mv[lane * 4];
  float4 p1 = *(const float4*)&s_post[256 + lane * 4];
  float4 m1 = *(const float4*)&s_mv[256 + lane * 4];

  float dP0 = 0.f, dM0 = 0.f, dP1 = 0.f, dM1 = 0.f;
  float dP2 = 0.f, dM2 = 0.f, dP3 = 0.f, dM3 = 0.f;

#define ACC(dP, dM, c, pp, mm)                        \
  {                                                   \
    float ox = (float)(c).x, oy = (float)(c).y,       \
          oz = (float)(c).z, ow = (float)(c).w;       \
    dP = fmaf(ox, (pp).x, dP); dM = fmaf(ox, (mm).x, dM); \
    dP = fmaf(oy, (pp).y, dP); dM = fmaf(oy, (mm).y, dM); \
    dP = fmaf(oz, (pp).z, dP); dM = fmaf(oz, (mm).z, dM); \
    dP = fmaf(ow, (pp).w, dP); dM = fmaf(ow, (mm).w, dM); \
  }
  ACC(dP0, dM0, v00, p0, m0) ACC(dP0, dM0, v01, p1, m1)
  ACC(dP1, dM1, v10, p0, m0) ACC(dP1, dM1, v11, p1, m1)
  ACC(dP2, dM2, v20, p0, m0) ACC(dP2, dM2, v21, p1, m1)
  ACC(dP3, dM3, v30, p0, m0) ACC(dP3, dM3, v31, p1, m1)
#undef ACC

#pragma unroll
  for (int m = 1; m < 64; m <<= 1) {
    dP0 += __shfl_xor(dP0, m); dM0 += __shfl_xor(dM0, m);
    dP1 += __shfl_xor(dP1, m); dM1 += __shfl_xor(dM1, m);
    dP2 += __shfl_xor(dP2, m); dM2 += __shfl_xor(dM2, m);
    dP3 += __shfl_xor(dP3, m); dM3 += __shfl_xor(dM3, m);
  }

  if (lane < 4) {
    int r = r0 + lane;
    if (r < B) {
      float dP = (lane == 0) ? dP0 : (lane == 1) ? dP1 : (lane == 2) ? dP2 : dP3;
      float dM = (lane == 0) ? dM0 : (lane == 1) ? dM1 : (lane == 2) ? dM2 : dM3;
      float cneg = (Sf - dP) * 0.5f;
      float mneg = (Mtot - dM) * 0.5f;
      int yr = y[r];
      float a = (yr == -1) ? cneg : (Sf - cneg);
      float x = a * scale;
      x = fminf(fmaxf(x, 0.0f), (float)(MTAB_N - 1) - 1.001f);
      int i = (int)x;
      float fr = x - (float)i;
      float t0 = mtab[i], t1 = mtab[i + 1];
      float margin = fmaf(fr, t1 - t0, t0);
      float4 o4 = make_float4(margin, mneg, 1.0f - mneg, klf);
      *(float4*)(dout + (size_t)r * 4) = o4;
    }
  }
}

extern "C" void kernel_launch(void* const* d_in, const int* in_sizes, int n_in,
                              void* d_out, int out_size, void* d_ws,
                              size_t ws_size, hipStream_t stream) {
  const float* post_log = (const float*)d_in[0];
  const float* prior = (const float*)d_in[1];
  const int* vout = (const int*)d_in[2];
  const int* y = (const int*)d_in[3];
  float* dout = (float*)d_out;
  int B = in_sizes[3];
  unsigned char* ws = (unsigned char*)d_ws;

  hipLaunchKernelGGL(smv_setup_kernel, dim3(1 + MTAB_N / 512), dim3(512), 0,
                     stream, post_log, prior, ws);
  int blocks = (B + 31) / 32;
  hipLaunchKernelGGL(smv_main_kernel, dim3(blocks), dim3(512), 0, stream,
                     vout, y, ws, dout, B);
}

// Round 24
// 60.911 us; speedup vs baseline: 2.0527x; 1.2012x over previous
//
#include <hip/hip_runtime.h>
#include <math.h>

// ---------------------------------------------------------------------------
// Round 24: main-kernel reduction restructure (48->28 DS ops: 3 butterfly
// rounds + lane-select + 3 rounds + 1 shfl), y[] prefetched as int4 before
// the accumulate. Setup: divide-free Legendre recurrence (parallel 1/k LDS
// table), two-pass branch-free logsumexp in mtab blocks. Gamma/KL/mv chain
// (R20, verified) bit-exact untouched.
// Predicted: dur 73.2 -> ~62 us; absmax stays 0.05078125.
// ---------------------------------------------------------------------------

struct K2 { unsigned a, b; };

__device__ __forceinline__ unsigned rotl32(unsigned v, int r) {
  return (v << r) | (v >> (32 - r));
}

__device__ __forceinline__ K2 tf2x32(K2 k, unsigned x0, unsigned x1) {
  unsigned ks0 = k.a, ks1 = k.b, ks2 = k.a ^ k.b ^ 0x1BD11BDAu;
  x0 += ks0; x1 += ks1;
#define TF_ROUND(r) { x0 += x1; x1 = rotl32(x1, (r)); x1 ^= x0; }
  TF_ROUND(13) TF_ROUND(15) TF_ROUND(26) TF_ROUND(6)
  x0 += ks1; x1 += ks2 + 1u;
  TF_ROUND(17) TF_ROUND(29) TF_ROUND(16) TF_ROUND(24)
  x0 += ks2; x1 += ks0 + 2u;
  TF_ROUND(13) TF_ROUND(15) TF_ROUND(26) TF_ROUND(6)
  x0 += ks0; x1 += ks1 + 3u;
  TF_ROUND(17) TF_ROUND(29) TF_ROUND(16) TF_ROUND(24)
  x0 += ks1; x1 += ks2 + 4u;
  TF_ROUND(13) TF_ROUND(15) TF_ROUND(26) TF_ROUND(6)
  x0 += ks2; x1 += ks0 + 5u;
#undef TF_ROUND
  return {x0, x1};
}

__device__ __forceinline__ void split2f(K2& key, K2& sub) {
  K2 c = tf2x32(key, 0u, 0u);
  sub = tf2x32(key, 0u, 1u);
  key = c;
}

__device__ __forceinline__ void split3f(K2& key, K2& xk, K2& Uk) {
  K2 c = tf2x32(key, 0u, 0u);
  xk = tf2x32(key, 0u, 1u);
  Uk = tf2x32(key, 0u, 2u);
  key = c;
}

__device__ __forceinline__ K2 split512_at(K2 k, int i) {
  return tf2x32(k, 0u, (unsigned)i);
}

__device__ __forceinline__ unsigned rbits32(K2 k) {
  K2 r = tf2x32(k, 0u, 0u);
  return r.a ^ r.b;
}

__device__ __forceinline__ float bits_to_u01(unsigned bits) {
  unsigned fb = (bits >> 9) | 0x3F800000u;
  return __uint_as_float(fb) - 1.0f;
}

// XLA ErfInv32 (Giles polynomial)
__device__ __forceinline__ float erfinv_xla(float x) {
#pragma clang fp contract(off)
  float w = -log1pf(-(x * x));
  float p;
  if (w < 5.0f) {
    w = w - 2.5f;
    p = 2.81022636e-08f;
    p = 3.43273939e-07f + p * w;
    p = -3.5233877e-06f + p * w;
    p = -4.39150654e-06f + p * w;
    p = 0.00021858087f + p * w;
    p = -0.00125372503f + p * w;
    p = -0.00417768164f + p * w;
    p = 0.246640727f + p * w;
    p = 1.50140941f + p * w;
  } else {
    w = sqrtf(w) - 3.0f;
    p = -0.000200214257f;
    p = 0.000100950558f + p * w;
    p = 0.00134934322f + p * w;
    p = -0.00367342844f + p * w;
    p = 0.00573950773f + p * w;
    p = -0.0076224613f + p * w;
    p = 0.00943887047f + p * w;
    p = 1.00167406f + p * w;
    p = 2.83297682f + p * w;
  }
  return p * x;
}

__device__ __forceinline__ float normal_from_key(K2 k) {
#pragma clang fp contract(off)
  const float lo = -0.99999994f;           // nextafterf(-1, 0)
  float f = bits_to_u01(rbits32(k));
  float u = f * 2.0f + lo;                 // f32(1 - lo) == 2.0f
  u = fmaxf(lo, u);
  return 1.41421356f * erfinv_xla(u);
}

// jax.random.loggamma (_gamma_one, log_space=True), f32, conditional boost,
// boost term via EXPONENTIAL: log_boost = log1p(-u)/alpha.   [R20, verified]
__device__ float gamma_one_log(K2 key, float alpha) {
#pragma clang fp contract(off)
  float alpha_orig = alpha;
  bool boost = (alpha >= 1.0f);
  float al = boost ? alpha : (alpha + 1.0f);
  float d = al - 0.33333334f;
  float c = 0.33333334f / sqrtf(9.0f * d);
  K2 sub;
  split2f(key, sub);
  float u_boost = bits_to_u01(rbits32(sub));
  float X = 0.0f, V = 1.0f, U = 2.0f;
  while ((U >= 1.0f - 0.0331f * (X * X)) &&
         (logf(U) >= 0.5f * X + d * ((1.0f - V) + logf(V)))) {
    K2 xk, Uk;
    split3f(key, xk, Uk);
    float x = 0.0f, v = -1.0f;
    while (v <= 0.0f) {
      K2 s2;
      split2f(xk, s2);
      x = normal_from_key(s2);
      v = 1.0f + x * c;
    }
    X = x * x;
    V = (v * v) * v;
    U = bits_to_u01(rbits32(Uk));
  }
  float log_sample = logf(d) + logf(V);
  if (boost) return log_sample;
  return log_sample + log1pf(-u_boost) / alpha_orig;
}

// fp64 special functions
__device__ __forceinline__ double digamma_d(double x) {
  double r = 0.0;
  while (x < 6.0) { r -= 1.0 / x; x += 1.0; }
  double f = 1.0 / (x * x);
  double ser = f * (1.0 / 12.0 -
               f * (1.0 / 120.0 -
               f * (1.0 / 252.0 -
               f * (1.0 / 240.0 -
               f * (1.0 / 132.0)))));
  return r + log(x) - 0.5 / x - ser;
}

__device__ __forceinline__ double lgamma_stir(double x) {
  double shift = 0.0;
  while (x < 8.0) { shift -= log(x); x += 1.0; }
  double f = 1.0 / (x * x);
  double ser = (1.0 / 12.0 -
               f * (1.0 / 360.0 -
               f * (1.0 / 1260.0 -
               f * (1.0 / 1680.0)))) / x;
  return shift + 0.918938533204672741780329736406 + (x - 0.5) * log(x) - x + ser;
}

// Block reductions (512 threads)
__device__ double breduce_sum(double* sd, double v) {
  int t = threadIdx.x;
  sd[t] = v; __syncthreads();
  for (int s = 256; s > 0; s >>= 1) {
    if (t < s) sd[t] += sd[t + s];
    __syncthreads();
  }
  double r = sd[0]; __syncthreads();
  return r;
}

__device__ float breduce_maxf(float* sf, float v) {
  int t = threadIdx.x;
  sf[t] = v; __syncthreads();
  for (int s = 256; s > 0; s >>= 1) {
    if (t < s) sf[t] = fmaxf(sf[t], sf[t + s]);
    __syncthreads();
  }
  float r = sf[0]; __syncthreads();
  return r;
}

__device__ float breduce_sumf(float* sf, float v) {
  int t = threadIdx.x;
  sf[t] = v; __syncthreads();
  for (int s = 256; s > 0; s >>= 1) {
    if (t < s) sf[t] += sf[t + s];
    __syncthreads();
  }
  float r = sf[0]; __syncthreads();
  return r;
}

// ---------------------------------------------------------------------------
// ws layout: [0..63] doubles: S, lgamma(S), kl, Mtot. floats at +64B:
//   postf[512] @0, mvf[512] @512, (reserved), mtab[16384] @1792
// ---------------------------------------------------------------------------
#define MTAB_N 16384

__global__ void __launch_bounds__(512) smv_setup_kernel(
    const float* __restrict__ post_log, const float* __restrict__ prior,
    unsigned char* __restrict__ ws) {
  double* wsd = (double*)ws;
  float* fbase = (float*)(ws + 64);
  float* postf = fbase;
  float* mvf = fbase + 512;
  float* mtab = fbase + 1792;
  int tid = threadIdx.x;
  __shared__ double sd[512];

  if (blockIdx.x == 0) {
    // gamma draw + mv + Mtot + KL + S  (R20 chain, bit-exact, unchanged)
    __shared__ float sf[512];
    float alpha = expf(post_log[tid]);
    postf[tid] = alpha;
    double p = (double)alpha;
    double S = breduce_sum(sd, p);

    K2 root = {0u, 1u};                     // jax.random.key(1)
    K2 kv = split512_at(root, tid);
    float lg = gamma_one_log(kv, alpha);
    float mx = breduce_maxf(sf, lg);
    float un = expf(lg - mx);
    float se = breduce_sumf(sf, un);
    float mvv = un / se;
    mvf[tid] = mvv;
    float mtot = breduce_sumf(sf, mvv);

    double pr = (double)prior[tid];
    double dgS = digamma_d(S);
    double t3 = (p - pr) * (digamma_d(p) - dgS);
    double sum_lgp = breduce_sum(sd, lgamma(p));
    double Spr = breduce_sum(sd, pr);
    double sum_lgpr = breduce_sum(sd, lgamma(pr));
    double sum_t3 = breduce_sum(sd, t3);
    if (tid == 0) {
      double kl = lgamma(S) - sum_lgp - (lgamma(Spr) - sum_lgpr) + sum_t3;
      wsd[0] = S;
      wsd[1] = lgamma(S);
      wsd[2] = kl;
      wsd[3] = (double)mtot;
    }
    return;
  }

  // blocks 1..32: self-contained margin-table computation
  __shared__ double sinv[257];
  if (tid < 256) sinv[tid + 1] = 1.0 / (double)(tid + 1);  // parallel divides
  double S = breduce_sum(sd, (double)expf(post_log[tid]));
  double lgS = lgamma(S);

  // GL-256 nodes: Tricomi guess + ONE Newton eval + ODE-corrected dp;
  // divide-free recurrence via sinv table.
  __shared__ float slt[256], sl1t[256], slw[256];
  if (tid < 256) {
    const int n = 256;
    const double nn = (double)n;
    double th = M_PI * (tid + 0.75) / (nn + 0.5);
    double corr = 1.0 - 1.0 / (8.0 * nn * nn) + 1.0 / (8.0 * nn * nn * nn);
    double x = corr * cos(th);
    double p0 = 1.0, p1 = x;
    for (int k = 2; k <= n; ++k) {
      double pk = ((2.0 * k - 1.0) * x * p1 - (k - 1.0) * p0) * sinv[k];
      p0 = p1; p1 = pk;
    }
    double dp = nn * (x * p1 - p0) / (x * x - 1.0);
    double dx = -p1 / dp;                       // Newton step
    double d2p = (2.0 * x * dp - nn * (nn + 1.0) * p1) / (1.0 - x * x);
    double xn = x + dx;
    double dpn = dp + d2p * dx;
    double w = 2.0 / ((1.0 - xn * xn) * dpn * dpn);
    double t = 0.25 * (xn + 1.0);
    slt[tid] = (float)log(t);
    sl1t[tid] = (float)log1p(-t);
    slw[tid] = (float)log(0.25 * w);
  }
  __syncthreads();

  // one margin point per thread; two-pass branch-free logsumexp
  int idx = (blockIdx.x - 1) * 512 + tid;
  double ad = S * (double)idx / (double)(MTAB_N - 1);
  ad = fmin(fmax(ad, 0.05), S - 0.05);
  float a = (float)ad;
  float b = (float)(S - ad);
  float am1 = a - 1.0f, bm1 = b - 1.0f;

  float m0 = -1e30f, m1 = -1e30f, m2 = -1e30f, m3 = -1e30f;
#pragma unroll 4
  for (int q = 0; q < 256; q += 4) {
    m0 = fmaxf(m0, slw[q + 0] + am1 * slt[q + 0] + bm1 * sl1t[q + 0]);
    m1 = fmaxf(m1, slw[q + 1] + am1 * slt[q + 1] + bm1 * sl1t[q + 1]);
    m2 = fmaxf(m2, slw[q + 2] + am1 * slt[q + 2] + bm1 * sl1t[q + 2]);
    m3 = fmaxf(m3, slw[q + 3] + am1 * slt[q + 3] + bm1 * sl1t[q + 3]);
  }
  float m = fmaxf(fmaxf(m0, m1), fmaxf(m2, m3));
  float s0 = 0.f, s1 = 0.f, s2 = 0.f, s3 = 0.f;
#pragma unroll 4
  for (int q = 0; q < 256; q += 4) {
    s0 += expf(slw[q + 0] + am1 * slt[q + 0] + bm1 * sl1t[q + 0] - m);
    s1 += expf(slw[q + 1] + am1 * slt[q + 1] + bm1 * sl1t[q + 1] - m);
    s2 += expf(slw[q + 2] + am1 * slt[q + 2] + bm1 * sl1t[q + 2] - m);
    s3 += expf(slw[q + 3] + am1 * slt[q + 3] + bm1 * sl1t[q + 3] - m);
  }
  float lse = m + logf((s0 + s1) + (s2 + s3));
  double logB = lgamma_stir(ad) + lgamma_stir((double)(S - ad)) - lgS;
  double I = exp((double)lse - logB);
  mtab[idx] = (float)(1.0 - 2.0 * I);
}

// ---------------------------------------------------------------------------
// Main: 4 rows/wave (32/block). Dot-form accumulate; 28-DS reduction
// (3 rounds + select + 3 rounds + 1 shfl); y prefetched as int4; margin via
// table lerp. Reads out[B,512] once, coalesced int4.
// ---------------------------------------------------------------------------
__global__ void __launch_bounds__(512) smv_main_kernel(
    const int* __restrict__ vout, const int* __restrict__ y,
    const unsigned char* __restrict__ ws, float* __restrict__ dout, int B) {
  __shared__ float s_post[512], s_mv[512];
  const double* wsd = (const double*)ws;
  const float* fbase = (const float*)(ws + 64);
  const float* mtab = fbase + 1792;
  int tid = threadIdx.x;
  s_post[tid] = fbase[tid];
  s_mv[tid] = fbase[512 + tid];
  float Sf = (float)wsd[0];
  float Mtot = (float)wsd[3];
  float klf = (float)wsd[2];
  float scale = (float)(MTAB_N - 1) / Sf;
  __syncthreads();

  int wave = tid >> 6, lane = tid & 63;
  int r0 = (blockIdx.x * 8 + wave) * 4;
  if (r0 >= B) return;

  const int4* rp0 = (const int4*)(vout + (size_t)r0 * 512);
  const int4* rp1 = (const int4*)(vout + (size_t)min(r0 + 1, B - 1) * 512);
  const int4* rp2 = (const int4*)(vout + (size_t)min(r0 + 2, B - 1) * 512);
  const int4* rp3 = (const int4*)(vout + (size_t)min(r0 + 3, B - 1) * 512);

  // issue all row loads + y prefetch up-front
  int4 v00 = rp0[lane], v01 = rp0[64 + lane];
  int4 v10 = rp1[lane], v11 = rp1[64 + lane];
  int4 v20 = rp2[lane], v21 = rp2[64 + lane];
  int4 v30 = rp3[lane], v31 = rp3[64 + lane];
  int4 yv = *(const int4*)(y + r0);        // r0 % 4 == 0 -> 16B aligned

  float4 p0 = *(const float4*)&s_post[lane * 4];
  float4 m0 = *(const float4*)&s_mv[lane * 4];
  float4 p1 = *(const float4*)&s_post[256 + lane * 4];
  float4 m1 = *(const float4*)&s_mv[256 + lane * 4];

  float dP0 = 0.f, dM0 = 0.f, dP1 = 0.f, dM1 = 0.f;
  float dP2 = 0.f, dM2 = 0.f, dP3 = 0.f, dM3 = 0.f;

#define ACC(dP, dM, c, pp, mm)                        \
  {                                                   \
    float ox = (float)(c).x, oy = (float)(c).y,       \
          oz = (float)(c).z, ow = (float)(c).w;       \
    dP = fmaf(ox, (pp).x, dP); dM = fmaf(ox, (mm).x, dM); \
    dP = fmaf(oy, (pp).y, dP); dM = fmaf(oy, (mm).y, dM); \
    dP = fmaf(oz, (pp).z, dP); dM = fmaf(oz, (mm).z, dM); \
    dP = fmaf(ow, (pp).w, dP); dM = fmaf(ow, (mm).w, dM); \
  }
  ACC(dP0, dM0, v00, p0, m0) ACC(dP0, dM0, v01, p1, m1)
  ACC(dP1, dM1, v10, p0, m0) ACC(dP1, dM1, v11, p1, m1)
  ACC(dP2, dM2, v20, p0, m0) ACC(dP2, dM2, v21, p1, m1)
  ACC(dP3, dM3, v30, p0, m0) ACC(dP3, dM3, v31, p1, m1)
#undef ACC

  // 3 butterfly rounds on all 8 values (reduce within 8-lane groups)
#pragma unroll
  for (int m = 1; m < 8; m <<= 1) {
    dP0 += __shfl_xor(dP0, m); dM0 += __shfl_xor(dM0, m);
    dP1 += __shfl_xor(dP1, m); dM1 += __shfl_xor(dM1, m);
    dP2 += __shfl_xor(dP2, m); dM2 += __shfl_xor(dM2, m);
    dP3 += __shfl_xor(dP3, m); dM3 += __shfl_xor(dM3, m);
  }
  // lane selects value (lane&7): 0..3 -> dP0..dP3, 4..7 -> dM0..dM3
  int g = lane & 7;
  float v = dP0;
  v = (g == 1) ? dP1 : v;
  v = (g == 2) ? dP2 : v;
  v = (g == 3) ? dP3 : v;
  v = (g == 4) ? dM0 : v;
  v = (g == 5) ? dM1 : v;
  v = (g == 6) ? dM2 : v;
  v = (g == 7) ? dM3 : v;
  // 3 rounds across groups -> every lane holds total of value (lane&7)
#pragma unroll
  for (int m = 8; m < 64; m <<= 1) v += __shfl_xor(v, m);
  float vM = __shfl_xor(v, 4);             // lane k (k<4): dM of row k

  if (lane < 4) {
    int r = r0 + lane;
    if (r < B) {
      float cneg = (Sf - v) * 0.5f;
      float mneg = (Mtot - vM) * 0.5f;
      int yr = (lane == 0) ? yv.x : (lane == 1) ? yv.y : (lane == 2) ? yv.z : yv.w;
      float a = (yr == -1) ? cneg : (Sf - cneg);
      float x = a * scale;
      x = fminf(fmaxf(x, 0.0f), (float)(MTAB_N - 1) - 1.001f);
      int i = (int)x;
      float fr = x - (float)i;
      float t0 = mtab[i], t1 = mtab[i + 1];
      float margin = fmaf(fr, t1 - t0, t0);
      float4 o4 = make_float4(margin, mneg, 1.0f - mneg, klf);
      *(float4*)(dout + (size_t)r * 4) = o4;
    }
  }
}

extern "C" void kernel_launch(void* const* d_in, const int* in_sizes, int n_in,
                              void* d_out, int out_size, void* d_ws,
                              size_t ws_size, hipStream_t stream) {
  const float* post_log = (const float*)d_in[0];
  const float* prior = (const float*)d_in[1];
  const int* vout = (const int*)d_in[2];
  const int* y = (const int*)d_in[3];
  float* dout = (float*)d_out;
  int B = in_sizes[3];
  unsigned char* ws = (unsigned char*)d_ws;

  hipLaunchKernelGGL(smv_setup_kernel, dim3(1 + MTAB_N / 512), dim3(512), 0,
                     stream, post_log, prior, ws);
  int blocks = (B + 31) / 32;
  hipLaunchKernelGGL(smv_main_kernel, dim3(blocks), dim3(512), 0, stream,
                     vout, y, ws, dout, B);
}